// Round 2
// baseline (178.021 us; speedup 1.0000x reference)
//
#include <hip/hip_runtime.h>

typedef __bf16 bf16;
typedef __bf16 bf16x4 __attribute__((ext_vector_type(4)));
typedef __bf16 bf16x8 __attribute__((ext_vector_type(8)));
typedef float  f32x4  __attribute__((ext_vector_type(4)));

#define T_DIM 256
#define B_DIM 256
#define NIN   512
#define NH    512
#define NEMB  256
#define NX    768      // NIN + NEMB
#define NG    1536     // 3*NH

__device__ __forceinline__ float fast_tanh(float x) {
    float e = __expf(2.0f * x);
    return 1.0f - 2.0f * __builtin_amdgcn_rcpf(e + 1.0f);
}
__device__ __forceinline__ float fast_sigmoid(float x) {
    return __builtin_amdgcn_rcpf(1.0f + __expf(-x));
}

// ---------------- f32 -> bf16 convert (vectorized) ----------------
__global__ void cvt_f32_bf16(const float* __restrict__ s, bf16* __restrict__ d, int n4) {
    int i = blockIdx.x * blockDim.x + threadIdx.x;
    if (i >= n4) return;
    float4 v = reinterpret_cast<const float4*>(s)[i];
    bf16x4 o = { (bf16)v.x, (bf16)v.y, (bf16)v.z, (bf16)v.w };
    reinterpret_cast<bf16x4*>(d)[i] = o;
}

// ---------------- generic GEMM: C[M,N] = A[M,K] * B[N,K]^T + bias[N] ----------------
// A, B pre-converted bf16 row-major. Block = 256 thr (4 waves), tile 64m x 64n.
__global__ __launch_bounds__(256) void gemm_bias(
    const bf16* __restrict__ A, const bf16* __restrict__ B,
    const float* __restrict__ bias, float* __restrict__ C,
    int M, int N, int K) {
    __shared__ bf16 At[64][40];   // 32 k + 8 pad -> 80B stride, 2-way (free)
    __shared__ bf16 Bt[64][40];
    const int tid = threadIdx.x;
    const int m0 = blockIdx.y * 64, n0 = blockIdx.x * 64;
    const int wid = tid >> 6, lane = tid & 63, hi = lane >> 4, lo = lane & 15;
    const int srow = tid >> 2, sseg = tid & 3;
    f32x4 acc[4] = {};

    for (int kk = 0; kk < K; kk += 32) {
        bf16x8 av = *reinterpret_cast<const bf16x8*>(A + (size_t)(m0 + srow) * K + kk + sseg * 8);
        bf16x8 bv = *reinterpret_cast<const bf16x8*>(B + (size_t)(n0 + srow) * K + kk + sseg * 8);
        __syncthreads();   // protect previous iteration's reads
        *reinterpret_cast<bf16x8*>(&At[srow][sseg * 8]) = av;
        *reinterpret_cast<bf16x8*>(&Bt[srow][sseg * 8]) = bv;
        __syncthreads();
        bf16x8 a = *reinterpret_cast<const bf16x8*>(&At[wid * 16 + lo][hi * 8]);
#pragma unroll
        for (int nt = 0; nt < 4; ++nt) {
            bf16x8 b = *reinterpret_cast<const bf16x8*>(&Bt[nt * 16 + lo][hi * 8]);
            acc[nt] = __builtin_amdgcn_mfma_f32_16x16x32_bf16(a, b, acc[nt], 0, 0, 0);
        }
    }
#pragma unroll
    for (int nt = 0; nt < 4; ++nt) {
        int n = n0 + nt * 16 + lo;
        float bv = bias[n];
#pragma unroll
        for (int r = 0; r < 4; ++r) {
            int m = m0 + wid * 16 + hi * 4 + r;
            C[(size_t)m * N + n] = acc[nt][r] + bv;
        }
    }
}

// ---------------- fused emit kernel ----------------
// emit[m] = sum_n tanh(feats_[m,n] + h_[b(m),n]) * w_score[n],  feats_ = feats * W^T
// block: 64 rows of m (= t*B+b), 8 waves x 64 cols each, full K=512 in registers.
__global__ __launch_bounds__(512, 4) void emit_kernel(
    const float* __restrict__ feats, const bf16* __restrict__ W,
    const float* __restrict__ hbuf, const float* __restrict__ wscore,
    float* __restrict__ emit_out) {
    __shared__ char smem[65536];                  // 64KB: feats tile, later aliased as ew
    bf16* Atile = reinterpret_cast<bf16*>(smem);  // [64][512] bf16, XOR-swizzled
    const int tid = threadIdx.x;
    const int m0 = blockIdx.x * 64;

    // stage feats (f32 -> bf16) into swizzled LDS; fully coalesced float4 loads
#pragma unroll
    for (int it = 0; it < 16; ++it) {
        int idx = it * 512 + tid;          // 0..8191
        int row = idx >> 7;                // 0..63
        int c4  = idx & 127;               // float4 index in row
        float4 v = *reinterpret_cast<const float4*>(feats + (size_t)(m0 + row) * NIN + c4 * 4);
        bf16x4 o = { (bf16)v.x, (bf16)v.y, (bf16)v.z, (bf16)v.w };
        int el = row * 512 + ((c4 * 4) ^ ((row & 7) << 3));
        *reinterpret_cast<bf16x4*>(Atile + el) = o;
    }
    __syncthreads();

    const int wid = tid >> 6, lane = tid & 63, hi = lane >> 4, lo = lane & 15;
    const int n0 = wid * 64;
    f32x4 acc[4][4] = {};   // [nt][st]

    for (int kk = 0; kk < 16; ++kk) {
        bf16x8 a[4];
#pragma unroll
        for (int st = 0; st < 4; ++st) {
            int row = st * 16 + lo;
            int el = row * 512 + (((kk * 32) + hi * 8) ^ ((row & 7) << 3));
            a[st] = *reinterpret_cast<const bf16x8*>(Atile + el);
        }
#pragma unroll
        for (int nt = 0; nt < 4; ++nt) {
            bf16x8 b = *reinterpret_cast<const bf16x8*>(
                W + (size_t)(n0 + nt * 16 + lo) * NIN + kk * 32 + hi * 8);
#pragma unroll
            for (int st = 0; st < 4; ++st)
                acc[nt][st] = __builtin_amdgcn_mfma_f32_16x16x32_bf16(a[st], b, acc[nt][st], 0, 0, 0);
        }
    }

    // epilogue: add h_, tanh, dot with w_score — all in registers
    float ep[4][4] = {};                 // [st][r]
    const int bbase = m0 & (B_DIM - 1);  // 64-aligned, no wrap inside tile
#pragma unroll
    for (int nt = 0; nt < 4; ++nt) {
        int n = n0 + nt * 16 + lo;
        float wsn = wscore[n];
#pragma unroll
        for (int st = 0; st < 4; ++st) {
#pragma unroll
            for (int r = 0; r < 4; ++r) {
                int b = bbase + st * 16 + hi * 4 + r;
                float x = acc[nt][st][r] + hbuf[(size_t)b * NH + n];
                ep[st][r] += fast_tanh(x) * wsn;
            }
        }
    }
    // reduce over the 16 lanes (lo) that share each output row
#pragma unroll
    for (int st = 0; st < 4; ++st)
#pragma unroll
        for (int r = 0; r < 4; ++r)
#pragma unroll
            for (int off = 1; off < 16; off <<= 1)
                ep[st][r] += __shfl_xor(ep[st][r], off, 64);

    __syncthreads();   // everyone done reading Atile; safe to alias
    float* ew = reinterpret_cast<float*>(smem);   // [8][64]
    if (lo == 0) {
#pragma unroll
        for (int st = 0; st < 4; ++st)
#pragma unroll
            for (int r = 0; r < 4; ++r)
                ew[wid * 64 + st * 16 + hi * 4 + r] = ep[st][r];
    }
    __syncthreads();
    if (tid < 64) {
        float s = 0.0f;
#pragma unroll
        for (int ww = 0; ww < 8; ++ww) s += ew[ww * 64 + tid];
        emit_out[m0 + tid] = s;
    }
}

// ---------------- softmax over T (per column b) ----------------
__global__ __launch_bounds__(256) void softmax_t(
    const float* __restrict__ emit, float* __restrict__ alpha, float* __restrict__ out_alpha) {
    int b = blockIdx.x, t = threadIdx.x;
    int wv = t >> 6, ln = t & 63;
    float e = emit[(size_t)t * B_DIM + b];
    float m = e;
#pragma unroll
    for (int off = 32; off; off >>= 1) m = fmaxf(m, __shfl_xor(m, off, 64));
    __shared__ float red[4], red2[4];
    if (ln == 0) red[wv] = m;
    __syncthreads();
    m = fmaxf(fmaxf(red[0], red[1]), fmaxf(red[2], red[3]));
    float p = __expf(e - m);
    float s = p;
#pragma unroll
    for (int off = 32; off; off >>= 1) s += __shfl_xor(s, off, 64);
    if (ln == 0) red2[wv] = s;
    __syncthreads();
    float inv = __builtin_amdgcn_rcpf(red2[0] + red2[1] + red2[2] + red2[3]);
    float a = p * inv;
    alpha[(size_t)t * B_DIM + b] = a;
    out_alpha[(size_t)t * B_DIM + b] = a;
}

// ---------------- context[b,c] = sum_t alpha[t,b] * feats[t,b,c] ----------------
__global__ __launch_bounds__(256) void ctx_kernel(
    const float* __restrict__ feats, const float* __restrict__ alpha, float* __restrict__ ctx) {
    int b = blockIdx.y, c = blockIdx.x * 256 + threadIdx.x;
    __shared__ float al[T_DIM];
    al[threadIdx.x] = alpha[(size_t)threadIdx.x * B_DIM + b];
    __syncthreads();
    float acc = 0.0f;
#pragma unroll 8
    for (int t = 0; t < T_DIM; ++t)
        acc += al[t] * feats[((size_t)(t * B_DIM + b)) * NIN + c];
    ctx[(size_t)b * NIN + c] = acc;
}

// ---------------- x = concat(context, cur_embed), to bf16 ----------------
__global__ void build_x(const float* __restrict__ ctx, const float* __restrict__ emb,
                        bf16* __restrict__ x) {
    int b = blockIdx.y;
    int c = blockIdx.x * 256 + threadIdx.x;   // 0..767
    float v = (c < NIN) ? ctx[(size_t)b * NIN + c] : emb[(size_t)b * NEMB + (c - NIN)];
    x[(size_t)b * NX + c] = (bf16)v;
}

// ---------------- GRU gates ----------------
__global__ void gru_kernel(const float* __restrict__ gi, const float* __restrict__ gh,
                           const float* __restrict__ h, float* __restrict__ out) {
    int idx = blockIdx.x * 256 + threadIdx.x;   // 0..131071
    int b = idx >> 9, j = idx & 511;
    const float* gib = gi + (size_t)b * NG;
    const float* ghb = gh + (size_t)b * NG;
    float r = fast_sigmoid(gib[j] + ghb[j]);
    float z = fast_sigmoid(gib[NH + j] + ghb[NH + j]);
    float n = fast_tanh(gib[2 * NH + j] + r * ghb[2 * NH + j]);
    out[idx] = (1.0f - z) * n + z * h[idx];
}

extern "C" void kernel_launch(void* const* d_in, const int* in_sizes, int n_in,
                              void* d_out, int out_size, void* d_ws, size_t ws_size,
                              hipStream_t stream) {
    const float* feats = (const float*)d_in[0];
    const float* h     = (const float*)d_in[1];
    const float* emb   = (const float*)d_in[2];
    const float* w_i2h = (const float*)d_in[3];
    const float* w_h2h = (const float*)d_in[4];
    const float* b_h2h = (const float*)d_in[5];
    const float* w_sc  = (const float*)d_in[6];
    const float* w_ih  = (const float*)d_in[7];
    const float* w_hh  = (const float*)d_in[8];
    const float* b_ih  = (const float*)d_in[9];
    const float* b_hh  = (const float*)d_in[10];
    float* out = (float*)d_out;

    char* ws = (char*)d_ws;
    bf16*  w_i2h_b = (bf16*)(ws);                 // 512*512*2      = 524288
    bf16*  w_h2h_b = (bf16*)(ws + 524288);        // 512*512*2      = 524288
    bf16*  w_ih_b  = (bf16*)(ws + 1048576);       // 1536*768*2     = 2359296
    bf16*  w_hh_b  = (bf16*)(ws + 3407872);       // 1536*512*2     = 1572864
    bf16*  h_b     = (bf16*)(ws + 4980736);       // 256*512*2      = 262144
    bf16*  x_b     = (bf16*)(ws + 5242880);       // 256*768*2      = 393216
    float* hbuf    = (float*)(ws + 5636096);      // 256*512*4      = 524288
    float* emit    = (float*)(ws + 6160384);      // 65536*4        = 262144
    float* alpha   = (float*)(ws + 6422528);      // 65536*4        = 262144
    float* ctxb    = (float*)(ws + 6684672);      // 256*512*4      = 524288
    float* gi      = (float*)(ws + 7208960);      // 256*1536*4     = 1572864
    float* gh      = (float*)(ws + 8781824);      // 256*1536*4     = 1572864
    // total: 10354688 bytes

    // 1) weight/h conversions to bf16
    cvt_f32_bf16<<<256,  256, 0, stream>>>(w_i2h, w_i2h_b, 65536);
    cvt_f32_bf16<<<256,  256, 0, stream>>>(w_h2h, w_h2h_b, 65536);
    cvt_f32_bf16<<<1152, 256, 0, stream>>>(w_ih,  w_ih_b,  294912);
    cvt_f32_bf16<<<768,  256, 0, stream>>>(w_hh,  w_hh_b,  196608);
    cvt_f32_bf16<<<128,  256, 0, stream>>>(h,     h_b,     32768);

    // 2) h_ = h @ w_h2h^T + b_h2h  [256,512]
    gemm_bias<<<dim3(8, 4), 256, 0, stream>>>(h_b, w_h2h_b, b_h2h, hbuf, 256, NH, NH);

    // 3) fused emit
    emit_kernel<<<1024, 512, 0, stream>>>(feats, w_i2h_b, hbuf, w_sc, emit);

    // 4) alpha = softmax_T(emit); also write output 1
    softmax_t<<<256, 256, 0, stream>>>(emit, alpha, out + 131072);

    // 5) context
    ctx_kernel<<<dim3(2, 256), 256, 0, stream>>>(feats, alpha, ctxb);

    // 6) x = concat(context, cur_embed) -> bf16
    build_x<<<dim3(3, 256), 256, 0, stream>>>(ctxb, emb, x_b);

    // 7) gi = x @ w_ih^T + b_ih ; gh = h @ w_hh^T + b_hh
    gemm_bias<<<dim3(24, 4), 256, 0, stream>>>(x_b, w_ih_b, b_ih, gi, 256, NG, NX);
    gemm_bias<<<dim3(24, 4), 256, 0, stream>>>(h_b, w_hh_b, b_hh, gh, 256, NG, NH);

    // 8) GRU gates -> nh (output 0)
    gru_kernel<<<512, 256, 0, stream>>>(gi, gh, h, out);
}